// Round 4
// baseline (210.126 us; speedup 1.0000x reference)
//
#include <hip/hip_runtime.h>
#include <math.h>

// OLCNN: x(B,1,9,9) -> conv3x3(16ch) -> sigmoid (relu no-op) -> maxpool2x2
//        floor (7x7->3x3) -> conv2 (16*3x3->32) -> sigmoid -> fc 32->4.
// B = 131072 fp32.  One thread = one sample; 512 blocks x 256 = 2 waves/SIMD
// (grid-pinned occupancy, so VGPRs are cheap).
//
// Round 4:
//  * prep kernel permutes weights into d_ws:
//      - w1/b1 channel-paired (o,o+1) and pre-scaled by log2e
//      - w2 band-permuted [pi][oc][24 x float2] * log2e: each oc-row/band is
//        48 CONTIGUOUS dwords -> 3x s_load_dwordx16 (R3's 9-dword fragments
//        caused lgkm stalls)
//      - fc_w channel-paired
//  * packed fp32 (v_pk_fma_f32, full-rate on CDNA): conv1 pairs channels
//    (x broadcast {x,x}, w as SGPR pair), conv2 pairs adjacent features
//    (sigmoids written straight into v2f halves), fc pairs channels.
//    ~11k scalar VALU -> ~6.4k packed inst.
//  * band loop (pi) ROLLED (body fits I$); per-band x loads (32) pinned with
//    empty inline asm => compiler cannot sink/remat them into the math
//    (R2/R3's VGPR=60/64 proved it was re-fetching x per use).

typedef float v2f __attribute__((ext_vector_type(2)));

#define BLOCK 256
#define LOG2E 1.4426950408889634f

// ws layout (floats)
#define OFF_W2B  0      // [3][32][24][2] = 4608   (w2 * log2e, band-pair perm)
#define OFF_W1P  4608   // [8][9][2]      = 144    (w1 * log2e, ch-paired)
#define OFF_B1P  4752   // [8][2]         = 16     (b1 * log2e, ch-paired)
#define OFF_FCWP 4768   // [4][16][2]     = 128    (fc_w ch-paired)
#define OFF_B2S  4896   // 32                      (b2 * log2e)
#define WS_FLOATS 4928

__device__ __forceinline__ float sig2(float s) {
    // arg pre-scaled by log2e: sigmoid = 1/(1+2^-s)
    return __builtin_amdgcn_rcpf(1.0f + __builtin_amdgcn_exp2f(-s));
}

__global__ void prep_kernel(const float* __restrict__ w1,
                            const float* __restrict__ b1,
                            const float* __restrict__ w2,
                            const float* __restrict__ b2,
                            const float* __restrict__ fcw,
                            float* __restrict__ ws) {
    int i = blockIdx.x * blockDim.x + threadIdx.x;
    if (i < 4608) {
        // w2b[pi][oc][j][h] = w2[oc][o*9 + pi*3 + pj]*log2e, m=2j+h, o=m/3, pj=m%3
        int h = i & 1;
        int q = i >> 1;
        int j = q % 24;
        int oc = (q / 24) % 32;
        int pi = q / (24 * 32);
        int m = 2 * j + h;
        int o = m / 3, pj = m % 3;
        ws[OFF_W2B + i] = w2[oc * 144 + o * 9 + pi * 3 + pj] * LOG2E;
    } else if (i < 4752) {
        int r = i - 4608;                       // [op][k][h]
        int h = r & 1, k = (r >> 1) % 9, op = (r >> 1) / 9;
        ws[i] = w1[(2 * op + h) * 9 + k] * LOG2E;
    } else if (i < 4768) {
        int r = i - 4752;                       // [op][h]
        int h = r & 1, op = r >> 1;
        ws[i] = b1[2 * op + h] * LOG2E;
    } else if (i < 4896) {
        int r = i - 4768;                       // [r][j][h]
        int h = r & 1, j = (r >> 1) % 16, rr = (r >> 1) / 16;
        ws[i] = fcw[rr * 32 + 2 * j + h];
    } else if (i < WS_FLOATS) {
        ws[i] = b2[i - OFF_B2S] * LOG2E;
    }
}

__global__ __launch_bounds__(BLOCK, 2) void olcnn_kernel(
    const float* __restrict__ xg,   // (B,81)
    const float* __restrict__ ws,   // permuted weights
    const float* __restrict__ fcb,  // (4,)
    float* __restrict__ out)        // (B,4)
{
    const int t = blockIdx.x * BLOCK + threadIdx.x;
    const float* xs = xg + (long long)t * 81;

    const v2f* w1p  = (const v2f*)(ws + OFF_W1P);
    const v2f* b1p  = (const v2f*)(ws + OFF_B1P);
    const v2f* w2b  = (const v2f*)(ws + OFF_W2B);
    const v2f* fcwp = (const v2f*)(ws + OFF_FCWP);
    const float* b2s = ws + OFF_B2S;

    float acc2[32];
    #pragma unroll
    for (int oc = 0; oc < 32; ++oc) acc2[oc] = b2s[oc];

    for (int pi = 0; pi < 3; ++pi) {            // rolled: body ~fits I$
        // x band rows 2pi..2pi+3, cols 0..7, broadcast to {x,x} pairs; pinned
        v2f xb[32];
        #pragma unroll
        for (int r = 0; r < 4; ++r)
            #pragma unroll
            for (int c = 0; c < 8; ++c) {
                float v = xs[(2 * pi + r) * 9 + c];
                asm volatile("" : "+v"(v));     // pin: no sink/remat
                xb[r * 8 + c] = (v2f){v, v};
            }

        v2f pp[24];                              // pooled band, feature-paired
        #pragma unroll
        for (int op = 0; op < 8; ++op) {         // channel pairs (2op, 2op+1)
            v2f wv[9];
            #pragma unroll
            for (int k = 0; k < 9; ++k) wv[k] = w1p[op * 9 + k];
            const v2f bb = b1p[op];
            #pragma unroll
            for (int pj = 0; pj < 3; ++pj) {
                v2f vmax;
                #pragma unroll
                for (int dh = 0; dh < 2; ++dh)
                    #pragma unroll
                    for (int dw = 0; dw < 2; ++dw) {
                        v2f s = bb;
                        #pragma unroll
                        for (int i = 0; i < 3; ++i)
                            #pragma unroll
                            for (int jj = 0; jj < 3; ++jj)
                                s = __builtin_elementwise_fma(
                                        xb[(dh + i) * 8 + 2 * pj + dw + jj],
                                        wv[i * 3 + jj], s);
                        if (dh == 0 && dw == 0) vmax = s;
                        else vmax = __builtin_elementwise_max(vmax, s);
                    }
                float h0 = sig2(vmax.x);         // channel 2op
                float h1 = sig2(vmax.y);         // channel 2op+1
                const int m0 = 6 * op + pj;      // band-feature index o*3+pj
                const int m1 = 6 * op + 3 + pj;
                if (m0 & 1) pp[m0 >> 1].y = h0; else pp[m0 >> 1].x = h0;
                if (m1 & 1) pp[m1 >> 1].y = h1; else pp[m1 >> 1].x = h1;
            }
        }

        // conv2 band: acc2[oc] += <w2 band row, pp>; rows are 48 contiguous
        // dwords in permuted layout -> 3x s_load_dwordx16 per row
        const v2f* wband = w2b + pi * 32 * 24;
        #pragma unroll
        for (int oc = 0; oc < 32; ++oc) {
            v2f a = pp[0] * wband[oc * 24];
            #pragma unroll
            for (int j = 1; j < 24; ++j)
                a = __builtin_elementwise_fma(pp[j], wband[oc * 24 + j], a);
            acc2[oc] += a.x + a.y;
        }
    }

    // h2 = sigmoid(acc2) packed into pairs; fc 32->4 packed
    v2f h2[16];
    #pragma unroll
    for (int oc = 0; oc < 32; ++oc) {
        float h = sig2(acc2[oc]);
        if (oc & 1) h2[oc >> 1].y = h; else h2[oc >> 1].x = h;
    }
    float o0, o1, o2, o3;
    {
        v2f a0 = h2[0] * fcwp[0], a1 = h2[0] * fcwp[16],
            a2 = h2[0] * fcwp[32], a3 = h2[0] * fcwp[48];
        #pragma unroll
        for (int j = 1; j < 16; ++j) {
            a0 = __builtin_elementwise_fma(h2[j], fcwp[0 * 16 + j], a0);
            a1 = __builtin_elementwise_fma(h2[j], fcwp[1 * 16 + j], a1);
            a2 = __builtin_elementwise_fma(h2[j], fcwp[2 * 16 + j], a2);
            a3 = __builtin_elementwise_fma(h2[j], fcwp[3 * 16 + j], a3);
        }
        o0 = fcb[0] + a0.x + a0.y;
        o1 = fcb[1] + a1.x + a1.y;
        o2 = fcb[2] + a2.x + a2.y;
        o3 = fcb[3] + a3.x + a3.y;
    }

    ((float4*)out)[t] = make_float4(o0, o1, o2, o3);
}

extern "C" void kernel_launch(void* const* d_in, const int* in_sizes, int n_in,
                              void* d_out, int out_size, void* d_ws, size_t ws_size,
                              hipStream_t stream) {
    const float* x   = (const float*)d_in[0];
    const float* w1  = (const float*)d_in[1];
    const float* b1  = (const float*)d_in[2];
    const float* w2  = (const float*)d_in[3];
    const float* b2  = (const float*)d_in[4];
    const float* fcw = (const float*)d_in[5];
    const float* fcb = (const float*)d_in[6];
    float* out = (float*)d_out;
    float* ws  = (float*)d_ws;        // needs 4928 floats (~19.3 KB)

    prep_kernel<<<dim3((WS_FLOATS + 255) / 256), dim3(256), 0, stream>>>(
        w1, b1, w2, b2, fcw, ws);

    const int nB = in_sizes[0] / 81;  // 131072, divisible by BLOCK
    olcnn_kernel<<<dim3(nB / BLOCK), dim3(BLOCK), 0, stream>>>(x, ws, fcb, out);
}

// Round 5
// 142.488 us; speedup vs baseline: 1.4747x; 1.4747x over previous
//
#include <hip/hip_runtime.h>
#include <math.h>

// OLCNN: x(B,1,9,9) -> conv3x3(16ch) -> sigmoid (relu no-op) -> maxpool2x2
//        floor (7x7->3x3) -> conv2 (16*3x3->32) -> sigmoid -> fc 32->4.
// B = 131072 fp32. One thread = one sample; 512 blocks x 256 = 2 waves/SIMD
// (grid-pinned occupancy).
//
// Round 5 — make every memory path deterministic:
//  * weights live in LDS (20 KB, staged once per block from the prep-permuted
//    ws buffer). All weight reads are ds_read at wave-uniform addresses =
//    broadcast, conflict-free, dual-pipe with VALU. R4 proved pointer-cast
//    global weight loads fall off the s_load path onto per-lane VMEM
//    (VALUBusy 33%->15%); LDS removes the gamble entirely.
//  * band (pi) loop rolled (#pragma unroll 1, body fits I$); x live set is
//    only 32 scalars/band, loads pinned with inline asm (no sink/remat).
//  * packed fp32 throughout (v_pk_fma_f32): conv1 pairs channels, conv2 pairs
//    features, fc pairs channels; acc2 kept as v2f (horizontal add deferred
//    to epilogue). {v,v} splats left inline for op_sel folding.

typedef float v2f __attribute__((ext_vector_type(2)));
typedef float f4  __attribute__((ext_vector_type(4)));
typedef f4 uf4 __attribute__((aligned(4)));   // align-4 dwordx4 (x rows are
                                              // only 4B-aligned)

#define BLOCK 256
#define LOG2E 1.4426950408889634f

// ws / LDS layout (floats)
#define OFF_W2B  0      // [3][32][24][2] = 4608  (w2 * log2e, band-pair perm)
#define OFF_W1P  4608   // [8][9][2]      = 144   (w1 * log2e, ch-paired)
#define OFF_B1P  4752   // [8][2]         = 16    (b1 * log2e, ch-paired)
#define OFF_FCWP 4768   // [4][16][2]     = 128   (fc_w ch-paired)
#define OFF_B2S  4896   // 32                     (b2 * log2e)
#define WS_FLOATS 4928
#define WS_PAD    5120  // pad to 256*20 so the LDS stage is 5 x float4/thread

__device__ __forceinline__ float sig2(float s) {
    // arg pre-scaled by log2e: sigmoid = 1/(1+2^-s)
    return __builtin_amdgcn_rcpf(1.0f + __builtin_amdgcn_exp2f(-s));
}

__global__ void prep_kernel(const float* __restrict__ w1,
                            const float* __restrict__ b1,
                            const float* __restrict__ w2,
                            const float* __restrict__ b2,
                            const float* __restrict__ fcw,
                            float* __restrict__ ws) {
    int i = blockIdx.x * blockDim.x + threadIdx.x;
    if (i < 4608) {
        // w2b[pi][oc][j][h] = w2[oc][o*9+pi*3+pj]*log2e, m=2j+h, o=m/3, pj=m%3
        int h = i & 1;
        int q = i >> 1;
        int j = q % 24;
        int oc = (q / 24) % 32;
        int pi = q / (24 * 32);
        int m = 2 * j + h;
        int o = m / 3, pj = m % 3;
        ws[OFF_W2B + i] = w2[oc * 144 + o * 9 + pi * 3 + pj] * LOG2E;
    } else if (i < 4752) {
        int r = i - 4608;                       // [op][k][h]
        int h = r & 1, k = (r >> 1) % 9, op = (r >> 1) / 9;
        ws[i] = w1[(2 * op + h) * 9 + k] * LOG2E;
    } else if (i < 4768) {
        int r = i - 4752;                       // [op][h]
        int h = r & 1, op = r >> 1;
        ws[i] = b1[2 * op + h] * LOG2E;
    } else if (i < 4896) {
        int r = i - 4768;                       // [r][j][h]
        int h = r & 1, j = (r >> 1) % 16, rr = (r >> 1) / 16;
        ws[i] = fcw[rr * 32 + 2 * j + h];
    } else if (i < WS_FLOATS) {
        ws[i] = b2[i - OFF_B2S] * LOG2E;
    }
}

__global__ __launch_bounds__(BLOCK, 2) void olcnn_kernel(
    const float* __restrict__ xg,   // (B,81)
    const float* __restrict__ ws,   // permuted weights (WS_PAD floats)
    const float* __restrict__ fcb,  // (4,)
    float* __restrict__ out)        // (B,4)
{
    __shared__ __align__(16) float lws[WS_PAD];
    const int tid = threadIdx.x;

    // stage weights global -> LDS, coalesced float4
    {
        const f4* s4 = (const f4*)ws;
        f4* d4 = (f4*)lws;
        #pragma unroll
        for (int i = 0; i < WS_PAD / 4 / BLOCK; ++i)
            d4[tid + BLOCK * i] = s4[tid + BLOCK * i];
    }
    __syncthreads();

    const v2f* w1p   = (const v2f*)(lws + OFF_W1P);
    const v2f* b1p   = (const v2f*)(lws + OFF_B1P);
    const v2f* w2b   = (const v2f*)(lws + OFF_W2B);
    const v2f* fcwp  = (const v2f*)(lws + OFF_FCWP);
    const float* b2s = lws + OFF_B2S;

    const int t = blockIdx.x * BLOCK + tid;
    const float* xs = xg + (long long)t * 81;

    v2f acc2[32];                      // pair-accumulators; bias in .x
    #pragma unroll
    for (int oc = 0; oc < 32; ++oc) acc2[oc] = (v2f){b2s[oc], 0.0f};

    #pragma unroll 1                   // keep body in I$; x live/band = 32
    for (int pi = 0; pi < 3; ++pi) {
        // x rows 2pi..2pi+3, cols 0..7 (2 x align-4 dwordx4 per row), pinned
        float xb[4][8];
        #pragma unroll
        for (int r = 0; r < 4; ++r) {
            const float* rp = xs + (2 * pi + r) * 9;
            f4 a = *(const uf4*)rp;
            f4 b = *(const uf4*)(rp + 4);
            xb[r][0] = a.x; xb[r][1] = a.y; xb[r][2] = a.z; xb[r][3] = a.w;
            xb[r][4] = b.x; xb[r][5] = b.y; xb[r][6] = b.z; xb[r][7] = b.w;
        }
        #pragma unroll
        for (int r = 0; r < 4; ++r)
            #pragma unroll
            for (int c = 0; c < 8; ++c)
                asm volatile("" : "+v"(xb[r][c]));   // pin: no sink/remat

        v2f pp[24];                    // pooled band, feature-paired
        #pragma unroll
        for (int op = 0; op < 8; ++op) {            // channel pair (2op,2op+1)
            v2f wv[9];
            #pragma unroll
            for (int k = 0; k < 9; ++k) wv[k] = w1p[op * 9 + k];  // ds_read
            const v2f bb = b1p[op];
            #pragma unroll
            for (int pj = 0; pj < 3; ++pj) {
                v2f vmax;
                #pragma unroll
                for (int dh = 0; dh < 2; ++dh)
                    #pragma unroll
                    for (int dw = 0; dw < 2; ++dw) {
                        v2f s = bb;
                        #pragma unroll
                        for (int i = 0; i < 3; ++i)
                            #pragma unroll
                            for (int jj = 0; jj < 3; ++jj) {
                                float xv = xb[dh + i][2 * pj + dw + jj];
                                s = __builtin_elementwise_fma(
                                        (v2f){xv, xv}, wv[i * 3 + jj], s);
                            }
                        if (dh == 0 && dw == 0) vmax = s;
                        else vmax = __builtin_elementwise_max(vmax, s);
                    }
                float h0 = sig2(vmax.x);            // channel 2op
                float h1 = sig2(vmax.y);            // channel 2op+1
                const int m0 = 6 * op + pj;         // band feature o*3+pj
                const int m1 = 6 * op + 3 + pj;
                if (m0 & 1) pp[m0 >> 1].y = h0; else pp[m0 >> 1].x = h0;
                if (m1 & 1) pp[m1 >> 1].y = h1; else pp[m1 >> 1].x = h1;
            }
        }

        // conv2 band: acc2[oc] += <w2 band row (48 contiguous floats), pp>
        const v2f* wband = w2b + pi * 32 * 24;
        #pragma unroll
        for (int oc = 0; oc < 32; ++oc) {
            v2f a = acc2[oc];
            #pragma unroll
            for (int j = 0; j < 24; ++j)
                a = __builtin_elementwise_fma(pp[j], wband[oc * 24 + j], a);
            acc2[oc] = a;
        }
    }

    // h2 = sigmoid(hadd(acc2)) packed; fc 32->4 packed
    v2f h2[16];
    #pragma unroll
    for (int oc = 0; oc < 32; ++oc) {
        float h = sig2(acc2[oc].x + acc2[oc].y);
        if (oc & 1) h2[oc >> 1].y = h; else h2[oc >> 1].x = h;
    }
    v2f a0 = h2[0] * fcwp[0],  a1 = h2[0] * fcwp[16],
        a2 = h2[0] * fcwp[32], a3 = h2[0] * fcwp[48];
    #pragma unroll
    for (int j = 1; j < 16; ++j) {
        a0 = __builtin_elementwise_fma(h2[j], fcwp[0 * 16 + j], a0);
        a1 = __builtin_elementwise_fma(h2[j], fcwp[1 * 16 + j], a1);
        a2 = __builtin_elementwise_fma(h2[j], fcwp[2 * 16 + j], a2);
        a3 = __builtin_elementwise_fma(h2[j], fcwp[3 * 16 + j], a3);
    }
    ((float4*)out)[t] = make_float4(fcb[0] + a0.x + a0.y,
                                    fcb[1] + a1.x + a1.y,
                                    fcb[2] + a2.x + a2.y,
                                    fcb[3] + a3.x + a3.y);
}

extern "C" void kernel_launch(void* const* d_in, const int* in_sizes, int n_in,
                              void* d_out, int out_size, void* d_ws, size_t ws_size,
                              hipStream_t stream) {
    const float* x   = (const float*)d_in[0];
    const float* w1  = (const float*)d_in[1];
    const float* b1  = (const float*)d_in[2];
    const float* w2  = (const float*)d_in[3];
    const float* b2  = (const float*)d_in[4];
    const float* fcw = (const float*)d_in[5];
    const float* fcb = (const float*)d_in[6];
    float* out = (float*)d_out;
    float* ws  = (float*)d_ws;        // needs WS_PAD floats (20.5 KB)

    prep_kernel<<<dim3((WS_FLOATS + 255) / 256), dim3(256), 0, stream>>>(
        w1, b1, w2, b2, fcw, ws);

    const int nB = in_sizes[0] / 81;  // 131072, divisible by BLOCK
    olcnn_kernel<<<dim3(nB / BLOCK), dim3(BLOCK), 0, stream>>>(x, ws, fcb, out);
}